// Round 13
// baseline (18142.877 us; speedup 1.0000x reference)
//
#include <hip/hip_runtime.h>
#include <hip/hip_fp16.h>

typedef _Float16 h2v __attribute__((ext_vector_type(2)));

__device__ __forceinline__ float fdot2(unsigned int a, unsigned int b, float c) {
    return __builtin_amdgcn_fdot2(__builtin_bit_cast(h2v, a),
                                  __builtin_bit_cast(h2v, b), c, false);
}

#define SCOPE_SYS __HIP_MEMORY_SCOPE_SYSTEM

// ---------------- fp32 -> fp16 convert (vectorized x4) ----------------
__global__ __launch_bounds__(256) void k_f2h(const float* __restrict__ src,
                                             __half* __restrict__ dst, int n4) {
    int i = blockIdx.x * 256 + threadIdx.x;
    if (i >= n4) return;
    float4 v = ((const float4*)src)[i];
    union { __half2 h[2]; uint2 u; } o;
    o.h[0] = __halves2half2(__float2half_rn(v.x), __float2half_rn(v.y));
    o.h[1] = __halves2half2(__float2half_rn(v.z), __float2half_rn(v.w));
    ((uint2*)dst)[i] = o.u;
}

__global__ __launch_bounds__(256) void k_bias(const float* __restrict__ a,
                                              const float* __restrict__ b,
                                              float* __restrict__ o) {
    int i = blockIdx.x * 256 + threadIdx.x;
    if (i < 4096) o[i] = a[i] + b[i];
}

// ---------------- x_gates GEMM: C[8192][4096] = A[8192][1024] @ B[4096][1024]^T + bias ----
__global__ __launch_bounds__(256) void k_gemm_xg(const __half* __restrict__ A,
                                                 const __half* __restrict__ B,
                                                 const float* __restrict__ bias,
                                                 __half* __restrict__ C) {
    __shared__ unsigned int As[128][20];
    __shared__ unsigned int Bs[128][20];
    const int tid = threadIdx.x;
    const int tx = tid & 15, ty = tid >> 4;
    const int m0 = blockIdx.x * 128, n0 = blockIdx.y * 128;
    float acc[8][8];
#pragma unroll
    for (int i = 0; i < 8; ++i)
#pragma unroll
        for (int j = 0; j < 8; ++j) acc[i][j] = 0.f;
    const unsigned int* Ag = (const unsigned int*)(A + (size_t)m0 * 1024);
    const unsigned int* Bg = (const unsigned int*)(B + (size_t)n0 * 1024);
    for (int k0 = 0; k0 < 512; k0 += 16) {
        __syncthreads();
#pragma unroll
        for (int j = 0; j < 2; ++j) {
            int qd = j * 256 + tid;
            int row = qd >> 2;
            int c4 = (qd & 3) << 2;
            uint4 va = *(const uint4*)(Ag + (size_t)row * 512 + k0 + c4);
            uint4 vb = *(const uint4*)(Bg + (size_t)row * 512 + k0 + c4);
            *(uint4*)&As[row][c4] = va;
            *(uint4*)&Bs[row][c4] = vb;
        }
        __syncthreads();
#pragma unroll
        for (int k2 = 0; k2 < 16; k2 += 2) {
            unsigned int a0[8], a1[8], b0[8], b1[8];
#pragma unroll
            for (int i = 0; i < 8; ++i) {
                uint2 v = *(const uint2*)&As[ty + 16 * i][k2];
                a0[i] = v.x; a1[i] = v.y;
            }
#pragma unroll
            for (int j = 0; j < 8; ++j) {
                uint2 v = *(const uint2*)&Bs[tx + 16 * j][k2];
                b0[j] = v.x; b1[j] = v.y;
            }
#pragma unroll
            for (int i = 0; i < 8; ++i)
#pragma unroll
                for (int j = 0; j < 8; ++j) {
                    acc[i][j] = fdot2(a0[i], b0[j], acc[i][j]);
                    acc[i][j] = fdot2(a1[i], b1[j], acc[i][j]);
                }
        }
    }
#pragma unroll
    for (int i = 0; i < 8; ++i) {
        int row = m0 + ty + 16 * i;
#pragma unroll
        for (int j = 0; j < 8; ++j) {
            int col = n0 + tx + 16 * j;
            C[(size_t)row * 4096 + col] = __float2half_rn(acc[i][j] + bias[col]);
        }
    }
}

// ---------------- persistent LSTM recurrence ----------------
// 32 blocks x 512 threads. 4-ROWS-PER-LANE layout (r13): lane = (unit
// u=tid>>4 in 0..31, k-chunk j=tid&15 of 64 halfs). Each lane computes all 4
// gate rows of its unit over its chunk -> the 8 hs quad-reads are REUSED
// across gates (32 -> 8 hs reads/lane), and after the 16-lane butterfly
// reduce every lane holds all 4 gate sums -> no gather shuffles. LDS-pipe
// instructions 57 -> 42/lane (r12 analysis: LDS pipe was the compute gate).
// Weights: 32 uint4/lane; segs 0..17 persistent in LDS (144KB), segs 18..31
// prefetched into registers BEFORE the poll (L2 latency hides under it).
// Handshake (r5/r12, best measured): system-scope relaxed 4B tagged stores
// {tag16|h16} one per unit; each poller lane reads ONE 8B word = two tagged
// halfs = its staged h2 dword. Tight spin, one barrier per step.
__global__ __launch_bounds__(512, 1) void k_lstm(const __half* __restrict__ Whh,
                                                 const __half* __restrict__ xg,
                                                 unsigned int* pub) { // [2][1024]
    __shared__ uint4 Wp[18][512];          // 144KB persistent weight segs 0..17
    __shared__ unsigned int hs[2][576];    // 16 chunks of 32 dwords, stride 36
    const int tid = threadIdx.x;
    const int b = blockIdx.x;              // 0..31
    const int u = tid >> 4;                // block-local unit 0..31
    const int j = tid & 15;                // k-chunk 0..15 (64 halfs)
    // gate q row base: Whh + (q*1024 + b*32 + u)*1024 + j*64 halfs
    const unsigned int* gw =
        (const unsigned int*)(Whh + ((size_t)b * 32 + u) * 1024 + j * 64);
    // seg s (0..31): gate q=s>>3, sub i=s&7 -> gw + q*524288 + i*4 (uints)
#pragma unroll
    for (int s = 0; s < 18; ++s)
        Wp[s][tid] = *(const uint4*)(gw + (s >> 3) * 524288 + (s & 7) * 4);
    const int soff = (tid >> 5) * 36 + (tid & 31);   // hs slot for h2-dword tid
    const int upub = b * 32 + u;                      // unit this lane may publish
    float c_state = 0.f;
    __syncthreads();

    for (int t = 0; t < 8192; ++t) {
        // prefetch streamed weight segs 18..31 + this step's 4 xg values
        // (all h-independent) BEFORE the poll; pin pv so they can't sink.
        uint4 pv[14];
#pragma unroll
        for (int i = 0; i < 14; ++i) {
            int s = 18 + i;
            pv[i] = *(const uint4*)(gw + (s >> 3) * 524288 + (s & 7) * 4);
        }
        float xv[4];
#pragma unroll
        for (int q = 0; q < 4; ++q)
            xv[q] = __half2float(xg[(size_t)t * 4096 + q * 1024 + b * 32 + u]);
#pragma unroll
        for (int i = 0; i < 14; ++i)
            asm volatile("" : "+v"(pv[i].x), "+v"(pv[i].y), "+v"(pv[i].z), "+v"(pv[i].w));
        unsigned int d = 0;
        if (t > 0) {
            const unsigned long long* src =
                (const unsigned long long*)(pub + (((t - 1) & 1) << 10)) + tid;
            const unsigned tt = (unsigned)t;
            unsigned long long v = __hip_atomic_load(src, __ATOMIC_RELAXED, SCOPE_SYS);
            unsigned lo = (unsigned)v, hi = (unsigned)(v >> 32);
            while ((lo >> 16) != tt || (hi >> 16) != tt) {
                v = __hip_atomic_load(src, __ATOMIC_RELAXED, SCOPE_SYS);
                lo = (unsigned)v; hi = (unsigned)(v >> 32);
            }
            d = (lo & 0xffffu) | (hi << 16);
        }
        const int p = t & 1;
        hs[p][soff] = d;
        __syncthreads();                   // the ONLY barrier per step
        // load this lane's h chunk ONCE (8 quads), reuse across all 4 gates
        const unsigned int* hsp = &hs[p][j * 36];
        uint4 h4[8];
#pragma unroll
        for (int i = 0; i < 8; ++i)
            h4[i] = *(const uint4*)(hsp + i * 4);
        float acc[4] = {0.f, 0.f, 0.f, 0.f};
#pragma unroll
        for (int q = 0; q < 4; ++q)
#pragma unroll
            for (int i = 0; i < 8; ++i) {
                int s = q * 8 + i;
                uint4 wv = (s < 18) ? Wp[s][tid] : pv[s - 18];
                acc[q] = fdot2(wv.x, h4[i].x, acc[q]);
                acc[q] = fdot2(wv.y, h4[i].y, acc[q]);
                acc[q] = fdot2(wv.z, h4[i].z, acc[q]);
                acc[q] = fdot2(wv.w, h4[i].w, acc[q]);
            }
        // butterfly reduce over the 16 k-lanes (bits 0..3); every lane ends
        // with all 4 complete gate sums -> no gather shuffles needed
#pragma unroll
        for (int q = 0; q < 4; ++q) {
            acc[q] += __shfl_xor(acc[q], 1);
            acc[q] += __shfl_xor(acc[q], 2);
            acc[q] += __shfl_xor(acc[q], 4);
            acc[q] += __shfl_xor(acc[q], 8);
            acc[q] += xv[q];
        }
        float gi = 1.f / (1.f + __expf(-acc[0]));
        float gf = 1.f / (1.f + __expf(-acc[1]));
        float gg = 2.f / (1.f + __expf(-2.f * acc[2])) - 1.f;
        float go = 1.f / (1.f + __expf(-acc[3]));
        c_state = gf * c_state + gi * gg;          // replicated per 16-lane group
        float hval = go * (2.f / (1.f + __expf(-2.f * c_state)) - 1.f);
        // publish: k-lane 0 of each unit-group stores its unit's h
        if (j == 0) {
            unsigned val = ((unsigned)(t + 1) << 16) |
                           (unsigned)__half_as_ushort(__float2half_rn(hval));
            __hip_atomic_store(pub + (p << 10) + upub, val,
                               __ATOMIC_RELAXED, SCOPE_SYS);
        }
    }
}

// ---------------- final projection: out = h_final @ W_out^T + b_out ----------------
__global__ __launch_bounds__(256) void k_proj(const unsigned int* __restrict__ hfin,
                                              const float* __restrict__ Wout,
                                              const float* __restrict__ bout,
                                              float* __restrict__ out) {
    __shared__ float red[256];
    const int o = blockIdx.x, tid = threadIdx.x;
    const float* wr = Wout + (size_t)o * 1024;
    float acc = 0.f;
#pragma unroll
    for (int j = 0; j < 4; ++j) {
        int e = j * 256 + tid;
        unsigned v = hfin[e];              // {tag16 | h16}
        acc += __half2float(__ushort_as_half((unsigned short)(v & 0xffffu))) * wr[e];
    }
    red[tid] = acc;
    __syncthreads();
    for (int s = 128; s > 0; s >>= 1) {
        if (tid < s) red[tid] += red[tid + s];
        __syncthreads();
    }
    if (tid == 0) out[o] = red[0] + bout[o];
}

extern "C" void kernel_launch(void* const* d_in, const int* in_sizes, int n_in,
                              void* d_out, int out_size, void* d_ws, size_t ws_size,
                              hipStream_t stream) {
    const float* input_seq = (const float*)d_in[0];
    const float* W_ih = (const float*)d_in[1];
    const float* W_hh = (const float*)d_in[2];
    const float* b_ih = (const float*)d_in[3];
    const float* b_hh = (const float*)d_in[4];
    const float* W_out = (const float*)d_in[5];
    const float* b_out = (const float*)d_in[6];
    float* out = (float*)d_out;

    char* ws = (char*)d_ws;
    unsigned int* pub = (unsigned int*)ws;                         // [0, 8KB): [2][1024] tagged h
    float* bias = (float*)(ws + 24576);                            // [24KB, 40KB)
    __half* Wih_h = (__half*)(ws + 65536);                         // 8MB
    __half* Whh_h = (__half*)(ws + 65536 + (size_t)8 * 1024 * 1024);   // 8MB
    __half* in_h  = (__half*)(ws + 65536 + (size_t)16 * 1024 * 1024);  // 16MB
    __half* xg    = (__half*)(ws + 65536 + (size_t)32 * 1024 * 1024);  // 64MB

    // clear tags each call (graph replay determinism)
    hipMemsetAsync(ws, 0, 8192, stream);

    k_f2h<<<8192, 256, 0, stream>>>(input_seq, in_h, 2 * 1024 * 1024);
    k_f2h<<<4096, 256, 0, stream>>>(W_ih, Wih_h, 1024 * 1024);
    k_f2h<<<4096, 256, 0, stream>>>(W_hh, Whh_h, 1024 * 1024);
    k_bias<<<16, 256, 0, stream>>>(b_ih, b_hh, bias);

    dim3 gg(64, 32);
    k_gemm_xg<<<gg, 256, 0, stream>>>(in_h, Wih_h, bias, xg);

    k_lstm<<<32, 512, 0, stream>>>(Whh_h, xg, pub);

    k_proj<<<1024, 256, 0, stream>>>(pub + 1024, W_out, b_out, out);
}